// Round 1
// baseline (1710.899 us; speedup 1.0000x reference)
//
#include <hip/hip_runtime.h>
#include <hip/hip_bf16.h>
#include <cstdint>
#include <cstddef>

#define B_  256
#define Z_  512
#define H_  2048
#define T_  16
#define H3_ 6144

using short8 = __attribute__((ext_vector_type(8))) short;
using bf16x8 = __attribute__((ext_vector_type(8))) __bf16;
using f32x4  = __attribute__((ext_vector_type(4))) float;

__device__ __forceinline__ f32x4 mfma_bf16(short8 a, short8 b, f32x4 c) {
  return __builtin_amdgcn_mfma_f32_16x16x32_bf16(
      __builtin_bit_cast(bf16x8, a), __builtin_bit_cast(bf16x8, b), c, 0, 0, 0);
}

__device__ __forceinline__ unsigned short f2bf(float f) {
  unsigned int u = __builtin_bit_cast(unsigned int, f);
  u = (u + 0x7FFFu + ((u >> 16) & 1u)) >> 16;
  return (unsigned short)u;
}

__device__ __forceinline__ float sigmoidf_(float x) { return 1.0f / (1.0f + __expf(-x)); }

// LDS XOR swizzle: tiles are [rows][64] bf16 (128 B rows = 8x16B chunks).
// chunk ^= (row&7) spreads same-chunk column reads across banks.
__device__ __forceinline__ int swz(int row, int chunk) {
  return row * 64 + ((chunk ^ (row & 7)) << 3);   // ushort element offset
}

// ---------------------------------------------------------------------------
// Generic bf16 GEMM, C = A @ B^T (+add)(+bias)(*scale), A:[M][K], B:[N][K].
// WG tile 32x64, 4 waves of 16x32. Grid = (M/32, N/64). K % 64 == 0.
// ---------------------------------------------------------------------------
__global__ __launch_bounds__(256) void gemm_bt(
    const unsigned short* __restrict__ A,
    const unsigned short* __restrict__ Bw,
    int K,
    const float* __restrict__ addsrc, int add_ld,
    const float* __restrict__ bias,
    const float* __restrict__ scale_ptr,
    unsigned short* __restrict__ out_bf,
    float* __restrict__ out_f, int ldo)
{
  __shared__ unsigned short sA[32 * 64];
  __shared__ unsigned short sB[64 * 64];
  const int tid  = threadIdx.x;
  const int m0   = blockIdx.x * 32, n0 = blockIdx.y * 64;
  const int wave = tid >> 6, lane = tid & 63;
  const int wr = wave & 1, wc = wave >> 1;
  const int q = lane >> 4, c16 = lane & 15;
  const int lr = tid >> 3, lc8 = tid & 7;
  f32x4 acc0 = {}, acc1 = {};
  const size_t rowA  = (size_t)(m0 + lr) * K;
  const size_t rowB0 = (size_t)(n0 + lr) * K;
  const size_t rowB1 = (size_t)(n0 + 32 + lr) * K;
  for (int k0 = 0; k0 < K; k0 += 64) {
    const int gc = k0 + lc8 * 8;
    uint4 ra  = *(const uint4*)(A  + rowA  + gc);
    uint4 rb0 = *(const uint4*)(Bw + rowB0 + gc);
    uint4 rb1 = *(const uint4*)(Bw + rowB1 + gc);
    __syncthreads();
    *(uint4*)(sA + swz(lr, lc8))      = ra;
    *(uint4*)(sB + swz(lr, lc8))      = rb0;
    *(uint4*)(sB + swz(32 + lr, lc8)) = rb1;
    __syncthreads();
#pragma unroll
    for (int kk = 0; kk < 2; ++kk) {
      const int arow = wr * 16 + c16;
      short8 af = *(const short8*)(sA + swz(arow, kk * 4 + q));
      const int brow = wc * 32 + c16;
      short8 b0 = *(const short8*)(sB + swz(brow, kk * 4 + q));
      acc0 = mfma_bf16(af, b0, acc0);
      short8 b1 = *(const short8*)(sB + swz(brow + 16, kk * 4 + q));
      acc1 = mfma_bf16(af, b1, acc1);
    }
  }
  const float scale = scale_ptr ? *scale_ptr : 1.0f;
#pragma unroll
  for (int cf = 0; cf < 2; ++cf) {
    f32x4 a = cf ? acc1 : acc0;
#pragma unroll
    for (int v = 0; v < 4; ++v) {
      const int row = m0 + wr * 16 + q * 4 + v;
      const int col = n0 + wc * 32 + cf * 16 + c16;
      float val = a[v] * scale;
      if (addsrc) val += addsrc[(size_t)row * add_ld + col];
      if (bias)   val += bias[col];
      if (out_f)  out_f[(size_t)row * ldo + col] = val;
      if (out_bf) out_bf[(size_t)row * ldo + col] = f2bf(val);
    }
  }
}

// ---------------------------------------------------------------------------
// Fused GRU step. A:[256][K] bf16 input, 4 weight mats [2048][K] bf16.
//   r = sig(A@Wr^T + cr); u = sig(A@Wz^T + cz)
//   n = tanh(A@Wn^T + cn + r*(A@Whn^T + chn)); h' = (1-u)*n + u*h_old
// Whn==null -> h_n acc = 0. h_old==null -> 0. Grid (8, 32), 256 thr.
// ---------------------------------------------------------------------------
__global__ __launch_bounds__(256) void gru_step(
    const unsigned short* __restrict__ A, int K,
    const unsigned short* __restrict__ Wr,
    const unsigned short* __restrict__ Wz,
    const unsigned short* __restrict__ Wn,
    const unsigned short* __restrict__ Whn,
    const float* __restrict__ cr, const float* __restrict__ cz,
    const float* __restrict__ cn, const float* __restrict__ chn,
    const float* __restrict__ h_old,
    float* __restrict__ h_new,
    unsigned short* __restrict__ h_hist)
{
  __shared__ unsigned short sA[32 * 64];
  __shared__ unsigned short sW[4][64 * 64];
  const int tid  = threadIdx.x;
  const int m0   = blockIdx.x * 32, n0 = blockIdx.y * 64;
  const int wave = tid >> 6, lane = tid & 63;
  const int wr = wave & 1, wc = wave >> 1;
  const int q = lane >> 4, c16 = lane & 15;
  const int lr = tid >> 3, lc8 = tid & 7;
  const bool has_hn = (Whn != nullptr);
  const int NG = has_hn ? 4 : 3;
  f32x4 acc[4][2] = {};
  const unsigned short* Wg[4] = {Wr, Wz, Wn, Whn};
  const size_t rowA = (size_t)(m0 + lr) * K;
  const size_t rw0  = (size_t)(n0 + lr) * K;
  const size_t rw1  = (size_t)(n0 + 32 + lr) * K;
  for (int k0 = 0; k0 < K; k0 += 64) {
    const int gc = k0 + lc8 * 8;
    uint4 ra = *(const uint4*)(A + rowA + gc);
    uint4 rw[4][2];
#pragma unroll
    for (int g = 0; g < 4; ++g) {
      if (g < NG) {
        rw[g][0] = *(const uint4*)(Wg[g] + rw0 + gc);
        rw[g][1] = *(const uint4*)(Wg[g] + rw1 + gc);
      }
    }
    __syncthreads();
    *(uint4*)(sA + swz(lr, lc8)) = ra;
#pragma unroll
    for (int g = 0; g < 4; ++g) {
      if (g < NG) {
        *(uint4*)(sW[g] + swz(lr, lc8))      = rw[g][0];
        *(uint4*)(sW[g] + swz(32 + lr, lc8)) = rw[g][1];
      }
    }
    __syncthreads();
#pragma unroll
    for (int kk = 0; kk < 2; ++kk) {
      const int arow = wr * 16 + c16;
      short8 af = *(const short8*)(sA + swz(arow, kk * 4 + q));
#pragma unroll
      for (int g = 0; g < 4; ++g) {
        if (g < NG) {
#pragma unroll
          for (int cf = 0; cf < 2; ++cf) {
            const int brow = wc * 32 + cf * 16 + c16;
            short8 bf = *(const short8*)(sW[g] + swz(brow, kk * 4 + q));
            acc[g][cf] = mfma_bf16(af, bf, acc[g][cf]);
          }
        }
      }
    }
  }
#pragma unroll
  for (int cf = 0; cf < 2; ++cf) {
#pragma unroll
    for (int v = 0; v < 4; ++v) {
      const int row = m0 + wr * 16 + q * 4 + v;
      const int col = n0 + wc * 32 + cf * 16 + c16;
      const float R   = sigmoidf_(acc[0][cf][v] + cr[col]);
      const float U   = sigmoidf_(acc[1][cf][v] + cz[col]);
      const float hnv = (has_hn ? acc[3][cf][v] : 0.0f) + chn[col];
      const float Nv  = tanhf(acc[2][cf][v] + cn[col] + R * hnv);
      const float ho  = h_old ? h_old[(size_t)row * H_ + col] : 0.0f;
      const float hv  = (1.0f - U) * Nv + U * ho;
      h_new[(size_t)row * H_ + col]  = hv;
      h_hist[(size_t)row * H_ + col] = f2bf(hv);
    }
  }
}

// ---------------------------------------------------------------------------
// small helpers
// ---------------------------------------------------------------------------
__global__ void quantk(const float* __restrict__ s, unsigned short* __restrict__ d, int n4) {
  int i = blockIdx.x * blockDim.x + threadIdx.x;
  if (i < n4) {
    float4 v = ((const float4*)s)[i];
    ushort4 o;
    o.x = f2bf(v.x); o.y = f2bf(v.y); o.z = f2bf(v.z); o.w = f2bf(v.w);
    ((ushort4*)d)[i] = o;
  }
}

// lin_w [512][2048] f32 -> lin_wT [2048][512] bf16
__global__ __launch_bounds__(256) void transq(const float* __restrict__ s,
                                              unsigned short* __restrict__ d) {
  __shared__ float tile[32][33];
  const int tx = threadIdx.x & 31, ty = threadIdx.x >> 5;
  const int k0 = blockIdx.x * 32, z0 = blockIdx.y * 32;
#pragma unroll
  for (int j = 0; j < 4; ++j)
    tile[ty + j * 8][tx] = s[(size_t)(z0 + ty + j * 8) * H_ + k0 + tx];
  __syncthreads();
#pragma unroll
  for (int j = 0; j < 4; ++j)
    d[(size_t)(k0 + ty + j * 8) * Z_ + z0 + tx] = f2bf(tile[tx][ty + j * 8]);
}

// spectral norm: t1 = W^T u ; t2 = W * normalize(t1); inv_sigma = 1/||t2||-ish
__global__ void sigma1(const float* __restrict__ W, const float* __restrict__ u,
                       float* __restrict__ t1) {
  int c = blockIdx.x * 256 + threadIdx.x;
  float s = 0.f;
  for (int r = 0; r < Z_; ++r) s += W[(size_t)r * Z_ + c] * u[r];
  t1[c] = s;
}
__global__ void sigma2(const float* __restrict__ W, const float* __restrict__ t1,
                       float* __restrict__ t2) {
  int r = blockIdx.x * 256 + threadIdx.x;
  float n1 = 0.f;
  for (int c = 0; c < Z_; ++c) { float v = t1[c]; n1 += v * v; }
  float inv = 1.0f / (sqrtf(n1) + 1e-12f);
  float s = 0.f;
  for (int c = 0; c < Z_; ++c) s += W[(size_t)r * Z_ + c] * t1[c];
  t2[r] = s * inv;
}
__global__ void sigma3(const float* __restrict__ t2, float* __restrict__ inv_sig) {
  __shared__ float red[256];
  int t = threadIdx.x;
  float v0 = t2[t], v1 = t2[t + 256];
  red[t] = v0 * v0 + v1 * v1;
  __syncthreads();
  for (int s = 128; s > 0; s >>= 1) {
    if (t < s) red[t] += red[t + s];
    __syncthreads();
  }
  if (t == 0) {
    float s2  = red[0];
    float sig = s2 / (sqrtf(s2) + 1e-12f);
    inv_sig[0] = 1.0f / sig;
  }
}

// dvec[row] = dot(w_ih[row], lin_b) for row in [0, 6144)
__global__ __launch_bounds__(256) void dots_k(const float* __restrict__ w,
                                              const float* __restrict__ lb,
                                              float* __restrict__ dvec) {
  const int wave = threadIdx.x >> 6, lane = threadIdx.x & 63;
#pragma unroll
  for (int i = 0; i < 4; ++i) {
    int row = blockIdx.x * 16 + wave * 4 + i;
    float s = 0.f;
    for (int c = lane; c < Z_; c += 64) s += w[(size_t)row * Z_ + c] * lb[c];
#pragma unroll
    for (int off = 32; off > 0; off >>= 1) s += __shfl_down(s, off);
    if (lane == 0) dvec[row] = s;
  }
}

__global__ void consts_k(const float* __restrict__ b_ih, const float* __restrict__ b_hh,
                         const float* __restrict__ dvec,
                         float* __restrict__ c0r, float* __restrict__ c0z,
                         float* __restrict__ c0n,
                         float* __restrict__ c1r, float* __restrict__ c1z,
                         float* __restrict__ c1n, float* __restrict__ chn) {
  int j = blockIdx.x * 256 + threadIdx.x;
  float br = b_ih[j], bz = b_ih[H_ + j], bn = b_ih[2 * H_ + j];
  float hr = b_hh[j], hz = b_hh[H_ + j], hn = b_hh[2 * H_ + j];
  c0r[j] = br + hr; c0z[j] = bz + hz; c0n[j] = bn; chn[j] = hn;
  c1r[j] = br + hr + dvec[j];
  c1z[j] = bz + hz + dvec[H_ + j];
  c1n[j] = bn + dvec[2 * H_ + j];
}

// BN over batch per (t,z) + transpose [T,B,Z] -> [B,T,Z]. Grid (16, 8).
__global__ __launch_bounds__(256) void bn_k(const float* __restrict__ outs,
                                            float* __restrict__ y) {
  __shared__ float s_sum[4][64], s_sq[4][64], s_mean[64], s_inv[64];
  const int t = blockIdx.x, zb = blockIdx.y;
  const int zl = threadIdx.x & 63, bp = threadIdx.x >> 6;
  const int z = zb * 64 + zl;
  float sum = 0.f, sq = 0.f;
  for (int b = bp * 64; b < bp * 64 + 64; ++b) {
    float v = outs[(size_t)(t * 256 + b) * Z_ + z];
    sum += v; sq += v * v;
  }
  s_sum[bp][zl] = sum; s_sq[bp][zl] = sq;
  __syncthreads();
  if (bp == 0) {
    float S = s_sum[0][zl] + s_sum[1][zl] + s_sum[2][zl] + s_sum[3][zl];
    float Q = s_sq[0][zl] + s_sq[1][zl] + s_sq[2][zl] + s_sq[3][zl];
    float mean = S * (1.0f / 256.0f);
    float var  = Q * (1.0f / 256.0f) - mean * mean;
    s_mean[zl] = mean;
    s_inv[zl]  = rsqrtf(var + 1e-5f);
  }
  __syncthreads();
  const float mean = s_mean[zl], inv = s_inv[zl];
  for (int b = bp * 64; b < bp * 64 + 64; ++b) {
    float v = outs[(size_t)(t * 256 + b) * Z_ + z];
    y[(size_t)(b * T_ + t) * Z_ + z] = (v - mean) * inv;
  }
}

// ---------------------------------------------------------------------------
extern "C" void kernel_launch(void* const* d_in, const int* in_sizes, int n_in,
                              void* d_out, int out_size, void* d_ws, size_t ws_size,
                              hipStream_t stream) {
  const float* z     = (const float*)d_in[0];
  const float* fc_w  = (const float*)d_in[1];
  const float* fc_b  = (const float*)d_in[2];
  const float* fc_u  = (const float*)d_in[3];
  const float* w_ih  = (const float*)d_in[4];
  const float* w_hh  = (const float*)d_in[5];
  const float* b_ih  = (const float*)d_in[6];
  const float* b_hh  = (const float*)d_in[7];
  const float* lin_w = (const float*)d_in[8];
  const float* lin_b = (const float*)d_in[9];
  float* out = (float*)d_out;

  char* ws = (char*)d_ws;
  size_t off = 0;
  auto alloc = [&](size_t bytes) -> void* {
    off = (off + 255) & ~(size_t)255;
    void* p = ws + off;
    off += bytes;
    return p;
  };
  unsigned short* w_ih_q   = (unsigned short*)alloc((size_t)H3_ * Z_ * 2);
  unsigned short* w_hhn_q  = (unsigned short*)alloc((size_t)H_ * H_ * 2);
  unsigned short* lin_w_q  = (unsigned short*)alloc((size_t)Z_ * H_ * 2);
  unsigned short* lin_wT_q = (unsigned short*)alloc((size_t)Z_ * H_ * 2);
  unsigned short* fc_w_q   = (unsigned short*)alloc((size_t)Z_ * Z_ * 2);
  unsigned short* z_q      = (unsigned short*)alloc((size_t)B_ * Z_ * 2);
  unsigned short* x0_q     = (unsigned short*)alloc((size_t)B_ * Z_ * 2);
  unsigned short* Wsum_r   = (unsigned short*)alloc((size_t)H_ * H_ * 2);
  unsigned short* Wsum_z   = (unsigned short*)alloc((size_t)H_ * H_ * 2);
  unsigned short* Wn_c     = (unsigned short*)alloc((size_t)H_ * H_ * 2);
  unsigned short* Hhist    = (unsigned short*)alloc((size_t)T_ * B_ * H_ * 2);
  float* h_f32 = (float*)alloc((size_t)2 * B_ * H_ * 4);
  float* outs  = (float*)alloc((size_t)T_ * B_ * Z_ * 4);
  float* c0r = (float*)alloc(H_ * 4);
  float* c0z = (float*)alloc(H_ * 4);
  float* c0n = (float*)alloc(H_ * 4);
  float* c1r = (float*)alloc(H_ * 4);
  float* c1z = (float*)alloc(H_ * 4);
  float* c1n = (float*)alloc(H_ * 4);
  float* chn = (float*)alloc(H_ * 4);
  float* dvec = (float*)alloc(H3_ * 4);
  float* t1v = (float*)alloc(Z_ * 4);
  float* t2v = (float*)alloc(Z_ * 4);
  float* invsig = (float*)alloc(256);
  (void)in_sizes; (void)n_in; (void)out_size; (void)ws_size;

  auto q4 = [&](const float* s, unsigned short* dst, size_t n) {
    int n4 = (int)(n / 4);
    quantk<<<dim3((n4 + 255) / 256), dim3(256), 0, stream>>>(s, dst, n4);
  };
  q4(z, z_q, (size_t)B_ * Z_);
  q4(fc_w, fc_w_q, (size_t)Z_ * Z_);
  q4(w_ih, w_ih_q, (size_t)H3_ * Z_);
  q4(w_hh + (size_t)2 * H_ * H_, w_hhn_q, (size_t)H_ * H_);
  q4(lin_w, lin_w_q, (size_t)Z_ * H_);
  transq<<<dim3(64, 16), 256, 0, stream>>>(lin_w, lin_wT_q);
  sigma1<<<2, 256, 0, stream>>>(fc_w, fc_u, t1v);
  sigma2<<<2, 256, 0, stream>>>(fc_w, t1v, t2v);
  sigma3<<<1, 256, 0, stream>>>(t2v, invsig);
  dots_k<<<384, 256, 0, stream>>>(w_ih, lin_b, dvec);
  consts_k<<<8, 256, 0, stream>>>(b_ih, b_hh, dvec, c0r, c0z, c0n, c1r, c1z, c1n, chn);

  // x0 = (z @ fc_w^T) * inv_sigma + fc_b   -> bf16
  gemm_bt<<<dim3(B_ / 32, Z_ / 64), 256, 0, stream>>>(
      z_q, fc_w_q, Z_, nullptr, 0, fc_b, invsig, x0_q, nullptr, Z_);

  // W_comb_g = w_ih_g @ lin_w (+ w_hh_g for r,z) -> bf16 [2048][2048]
  for (int g = 0; g < 3; ++g) {
    const float* adds = (g < 2) ? (w_hh + (size_t)g * H_ * H_) : nullptr;
    unsigned short* outw = (g == 0) ? Wsum_r : (g == 1) ? Wsum_z : Wn_c;
    gemm_bt<<<dim3(H_ / 32, H_ / 64), 256, 0, stream>>>(
        w_ih_q + (size_t)g * H_ * Z_, lin_wT_q, Z_, adds, H_, nullptr, nullptr,
        outw, nullptr, H_);
  }

  for (int t = 0; t < T_; ++t) {
    if (t == 0) {
      gru_step<<<dim3(B_ / 32, H_ / 64), 256, 0, stream>>>(
          x0_q, Z_,
          w_ih_q, w_ih_q + (size_t)H_ * Z_, w_ih_q + (size_t)2 * H_ * Z_, nullptr,
          c0r, c0z, c0n, chn, nullptr, h_f32, Hhist);
    } else {
      gru_step<<<dim3(B_ / 32, H_ / 64), 256, 0, stream>>>(
          Hhist + (size_t)(t - 1) * B_ * H_, H_,
          Wsum_r, Wsum_z, Wn_c, w_hhn_q,
          c1r, c1z, c1n, chn,
          h_f32 + (size_t)((t - 1) & 1) * B_ * H_,
          h_f32 + (size_t)(t & 1) * B_ * H_,
          Hhist + (size_t)t * B_ * H_);
    }
  }

  // outs[t*256+b][z] = Hhist[t][b] @ lin_w^T + lin_b   (f32)
  gemm_bt<<<dim3(T_ * B_ / 32, Z_ / 64), 256, 0, stream>>>(
      Hhist, lin_w_q, H_, nullptr, 0, lin_b, nullptr, nullptr, outs, Z_);

  bn_k<<<dim3(T_, Z_ / 64), 256, 0, stream>>>(outs, out);
}

// Round 2
// 541.601 us; speedup vs baseline: 3.1590x; 3.1590x over previous
//
#include <hip/hip_runtime.h>
#include <hip/hip_bf16.h>
#include <cstdint>
#include <cstddef>

#define B_  256
#define Z_  512
#define H_  2048
#define T_  16
#define H3_ 6144

using short8 = __attribute__((ext_vector_type(8))) short;
using bf16x8 = __attribute__((ext_vector_type(8))) __bf16;
using f32x4  = __attribute__((ext_vector_type(4))) float;

__device__ __forceinline__ f32x4 mfma_bf16(short8 a, short8 b, f32x4 c) {
  return __builtin_amdgcn_mfma_f32_16x16x32_bf16(
      __builtin_bit_cast(bf16x8, a), __builtin_bit_cast(bf16x8, b), c, 0, 0, 0);
}

__device__ __forceinline__ unsigned short f2bf(float f) {
  unsigned int u = __builtin_bit_cast(unsigned int, f);
  u = (u + 0x7FFFu + ((u >> 16) & 1u)) >> 16;
  return (unsigned short)u;
}

__device__ __forceinline__ float sigmoidf_(float x) { return 1.0f / (1.0f + __expf(-x)); }

// LDS XOR swizzle: tiles are [rows][64] bf16 (128 B rows = 8x16B chunks).
__device__ __forceinline__ int swz(int row, int chunk) {
  return row * 64 + ((chunk ^ (row & 7)) << 3);   // ushort element offset
}

// ---------------------------------------------------------------------------
// Fused GRU step, tile M=64 x (4 gates x 32 cols). Grid = 256 WGs (1D,
// XCD-swizzled so the 4 m-tiles of an n-group share one XCD's L2).
//   r = sig(A@Wr^T + cr); u = sig(A@Wz^T + cz)
//   n = tanh(A@Wn^T + cn + r*(hn_scale*(A@Whn^T) + chn)); h' = (1-u)*n + u*h_old
// ---------------------------------------------------------------------------
__global__ __launch_bounds__(256) void gru_step2(
    const unsigned short* __restrict__ A, int K,
    const unsigned short* __restrict__ Wr,
    const unsigned short* __restrict__ Wz,
    const unsigned short* __restrict__ Wn,
    const unsigned short* __restrict__ Whn,
    const float* __restrict__ cr, const float* __restrict__ cz,
    const float* __restrict__ cn, const float* __restrict__ chn,
    float hn_scale,
    const float* __restrict__ h_old,
    float* __restrict__ h_new,
    unsigned short* __restrict__ h_hist)
{
  __shared__ unsigned short sA[64 * 64];
  __shared__ unsigned short sW[4][32 * 64];
  const int bid = blockIdx.x;
  // decode swizzle: xcd = bid%8 == n_idx%8; 4 m-tiles of a group co-XCD.
  const int xcd = bid & 7, rest = bid >> 3;
  const int m_idx = rest & 3, grp = rest >> 2;
  const int n_idx = grp * 8 + xcd;              // [0,64)
  const int m0 = m_idx * 64, n0 = n_idx * 32;
  const int tid = threadIdx.x;
  const int wave = tid >> 6, lane = tid & 63;
  const int wr = wave & 1, wc = wave >> 1;
  const int q = lane >> 4, c16 = lane & 15;
  const int lr = tid >> 3, lc8 = tid & 7;

  f32x4 acc[4][2] = {};
  const size_t aoff = (size_t)(m0 + lr) * K;
  const size_t woff = (size_t)(n0 + lr) * K;
  const size_t a32  = (size_t)32 * K;

  uint4 ra0, ra1, rw0, rw1, rw2, rw3;
  auto LOAD = [&](int k0) {
    const int gc = k0 + lc8 * 8;
    ra0 = *(const uint4*)(A   + aoff + gc);
    ra1 = *(const uint4*)(A   + aoff + a32 + gc);
    rw0 = *(const uint4*)(Wr  + woff + gc);
    rw1 = *(const uint4*)(Wz  + woff + gc);
    rw2 = *(const uint4*)(Wn  + woff + gc);
    rw3 = *(const uint4*)(Whn + woff + gc);
  };

  const int nIter = K >> 6;
  LOAD(0);
  for (int it = 0; it < nIter; ++it) {
    *(uint4*)(sA + swz(lr, lc8))      = ra0;
    *(uint4*)(sA + swz(lr + 32, lc8)) = ra1;
    *(uint4*)(&sW[0][swz(lr, lc8)])   = rw0;
    *(uint4*)(&sW[1][swz(lr, lc8)])   = rw1;
    *(uint4*)(&sW[2][swz(lr, lc8)])   = rw2;
    *(uint4*)(&sW[3][swz(lr, lc8)])   = rw3;
    __syncthreads();
    if (it + 1 < nIter) LOAD((it + 1) << 6);
#pragma unroll
    for (int kk = 0; kk < 2; ++kk) {
      short8 af0 = *(const short8*)(sA + swz(wr * 32 + c16,      kk * 4 + q));
      short8 af1 = *(const short8*)(sA + swz(wr * 32 + 16 + c16, kk * 4 + q));
#pragma unroll
      for (int g = 0; g < 4; ++g) {
        short8 bf = *(const short8*)(&sW[g][swz(wc * 16 + c16, kk * 4 + q)]);
        acc[g][0] = mfma_bf16(af0, bf, acc[g][0]);
        acc[g][1] = mfma_bf16(af1, bf, acc[g][1]);
      }
    }
    __syncthreads();
  }

#pragma unroll
  for (int i = 0; i < 2; ++i) {
#pragma unroll
    for (int v = 0; v < 4; ++v) {
      const int row = m0 + wr * 32 + i * 16 + q * 4 + v;
      const int col = n0 + wc * 16 + c16;
      const float R   = sigmoidf_(acc[0][i][v] + cr[col]);
      const float U   = sigmoidf_(acc[1][i][v] + cz[col]);
      const float hnv = hn_scale * acc[3][i][v] + chn[col];
      const float Nv  = tanhf(acc[2][i][v] + cn[col] + R * hnv);
      const float ho  = h_old ? h_old[(size_t)row * H_ + col] : 0.0f;
      const float hv  = (1.0f - U) * Nv + U * ho;
      h_new[(size_t)row * H_ + col]  = hv;
      h_hist[(size_t)row * H_ + col] = f2bf(hv);
    }
  }
}

// ---------------------------------------------------------------------------
// Generic bf16 GEMM, C = A @ B^T (+add)(+bias)(*scale). WG tile 32x64.
// Grid = (M/32, N/64). Used only for the small x0 GEMM (M=256).
// ---------------------------------------------------------------------------
__global__ __launch_bounds__(256) void gemm_bt(
    const unsigned short* __restrict__ A,
    const unsigned short* __restrict__ Bw,
    int K,
    const float* __restrict__ addsrc, int add_ld,
    const float* __restrict__ bias,
    const float* __restrict__ scale_ptr,
    unsigned short* __restrict__ out_bf,
    float* __restrict__ out_f, int ldo)
{
  __shared__ unsigned short sA[32 * 64];
  __shared__ unsigned short sB[64 * 64];
  const int tid  = threadIdx.x;
  const int m0   = blockIdx.x * 32, n0 = blockIdx.y * 64;
  const int wave = tid >> 6, lane = tid & 63;
  const int wr = wave & 1, wc = wave >> 1;
  const int q = lane >> 4, c16 = lane & 15;
  const int lr = tid >> 3, lc8 = tid & 7;
  f32x4 acc0 = {}, acc1 = {};
  const size_t rowA  = (size_t)(m0 + lr) * K;
  const size_t rowB0 = (size_t)(n0 + lr) * K;
  const size_t rowB1 = (size_t)(n0 + 32 + lr) * K;
  for (int k0 = 0; k0 < K; k0 += 64) {
    const int gc = k0 + lc8 * 8;
    uint4 ra  = *(const uint4*)(A  + rowA  + gc);
    uint4 rb0 = *(const uint4*)(Bw + rowB0 + gc);
    uint4 rb1 = *(const uint4*)(Bw + rowB1 + gc);
    __syncthreads();
    *(uint4*)(sA + swz(lr, lc8))      = ra;
    *(uint4*)(sB + swz(lr, lc8))      = rb0;
    *(uint4*)(sB + swz(32 + lr, lc8)) = rb1;
    __syncthreads();
#pragma unroll
    for (int kk = 0; kk < 2; ++kk) {
      const int arow = wr * 16 + c16;
      short8 af = *(const short8*)(sA + swz(arow, kk * 4 + q));
      const int brow = wc * 32 + c16;
      short8 b0 = *(const short8*)(sB + swz(brow, kk * 4 + q));
      acc0 = mfma_bf16(af, b0, acc0);
      short8 b1 = *(const short8*)(sB + swz(brow + 16, kk * 4 + q));
      acc1 = mfma_bf16(af, b1, acc1);
    }
  }
  const float scale = scale_ptr ? *scale_ptr : 1.0f;
#pragma unroll
  for (int cf = 0; cf < 2; ++cf) {
    f32x4 a = cf ? acc1 : acc0;
#pragma unroll
    for (int v = 0; v < 4; ++v) {
      const int row = m0 + wr * 16 + q * 4 + v;
      const int col = n0 + wc * 32 + cf * 16 + c16;
      float val = a[v] * scale;
      if (addsrc) val += addsrc[(size_t)row * add_ld + col];
      if (bias)   val += bias[col];
      if (out_f)  out_f[(size_t)row * ldo + col] = val;
      if (out_bf) out_bf[(size_t)row * ldo + col] = f2bf(val);
    }
  }
}

// ---------------------------------------------------------------------------
// 64x64-tile bf16 GEMM, C = A @ B^T (+add)(+bias). Grid = (M/64, N/64).
// 4 waves of 32x32. Reg-prefetch pipeline.
// ---------------------------------------------------------------------------
__global__ __launch_bounds__(256) void gemm_bt64(
    const unsigned short* __restrict__ A,
    const unsigned short* __restrict__ Bw,
    int K,
    const float* __restrict__ addsrc, int add_ld,
    const float* __restrict__ bias,
    unsigned short* __restrict__ out_bf,
    float* __restrict__ out_f, int ldo)
{
  __shared__ unsigned short sA[64 * 64];
  __shared__ unsigned short sB[64 * 64];
  const int tid  = threadIdx.x;
  const int m0   = blockIdx.x * 64, n0 = blockIdx.y * 64;
  const int wave = tid >> 6, lane = tid & 63;
  const int wr = wave & 1, wc = wave >> 1;
  const int q = lane >> 4, c16 = lane & 15;
  const int lr = tid >> 3, lc8 = tid & 7;
  f32x4 acc[2][2] = {};
  const size_t aoff = (size_t)(m0 + lr) * K;
  const size_t boff = (size_t)(n0 + lr) * K;
  const size_t s32  = (size_t)32 * K;

  uint4 ra0, ra1, rb0, rb1;
  auto LOAD = [&](int k0) {
    const int gc = k0 + lc8 * 8;
    ra0 = *(const uint4*)(A  + aoff + gc);
    ra1 = *(const uint4*)(A  + aoff + s32 + gc);
    rb0 = *(const uint4*)(Bw + boff + gc);
    rb1 = *(const uint4*)(Bw + boff + s32 + gc);
  };

  const int nIter = K >> 6;
  LOAD(0);
  for (int it = 0; it < nIter; ++it) {
    *(uint4*)(sA + swz(lr, lc8))      = ra0;
    *(uint4*)(sA + swz(lr + 32, lc8)) = ra1;
    *(uint4*)(sB + swz(lr, lc8))      = rb0;
    *(uint4*)(sB + swz(lr + 32, lc8)) = rb1;
    __syncthreads();
    if (it + 1 < nIter) LOAD((it + 1) << 6);
#pragma unroll
    for (int kk = 0; kk < 2; ++kk) {
      short8 af0 = *(const short8*)(sA + swz(wr * 32 + c16,      kk * 4 + q));
      short8 af1 = *(const short8*)(sA + swz(wr * 32 + 16 + c16, kk * 4 + q));
      short8 bf0 = *(const short8*)(sB + swz(wc * 32 + c16,      kk * 4 + q));
      short8 bf1 = *(const short8*)(sB + swz(wc * 32 + 16 + c16, kk * 4 + q));
      acc[0][0] = mfma_bf16(af0, bf0, acc[0][0]);
      acc[0][1] = mfma_bf16(af0, bf1, acc[0][1]);
      acc[1][0] = mfma_bf16(af1, bf0, acc[1][0]);
      acc[1][1] = mfma_bf16(af1, bf1, acc[1][1]);
    }
    __syncthreads();
  }
#pragma unroll
  for (int i = 0; i < 2; ++i) {
#pragma unroll
    for (int j = 0; j < 2; ++j) {
#pragma unroll
      for (int v = 0; v < 4; ++v) {
        const int row = m0 + wr * 32 + i * 16 + q * 4 + v;
        const int col = n0 + wc * 32 + j * 16 + c16;
        float val = acc[i][j][v];
        if (addsrc) val += addsrc[(size_t)row * add_ld + col];
        if (bias)   val += bias[col];
        if (out_f)  out_f[(size_t)row * ldo + col] = val;
        if (out_bf) out_bf[(size_t)row * ldo + col] = f2bf(val);
      }
    }
  }
}

// ---------------------------------------------------------------------------
// small helpers
// ---------------------------------------------------------------------------
__global__ void quantk(const float* __restrict__ s, unsigned short* __restrict__ d, int n4) {
  int i = blockIdx.x * blockDim.x + threadIdx.x;
  if (i < n4) {
    float4 v = ((const float4*)s)[i];
    ushort4 o;
    o.x = f2bf(v.x); o.y = f2bf(v.y); o.z = f2bf(v.z); o.w = f2bf(v.w);
    ((ushort4*)d)[i] = o;
  }
}

// lin_w [512][2048] f32 -> lin_wT [2048][512] bf16
__global__ __launch_bounds__(256) void transq(const float* __restrict__ s,
                                              unsigned short* __restrict__ d) {
  __shared__ float tile[32][33];
  const int tx = threadIdx.x & 31, ty = threadIdx.x >> 5;
  const int k0 = blockIdx.x * 32, z0 = blockIdx.y * 32;
#pragma unroll
  for (int j = 0; j < 4; ++j)
    tile[ty + j * 8][tx] = s[(size_t)(z0 + ty + j * 8) * H_ + k0 + tx];
  __syncthreads();
#pragma unroll
  for (int j = 0; j < 4; ++j)
    d[(size_t)(k0 + ty + j * 8) * Z_ + z0 + tx] = f2bf(tile[tx][ty + j * 8]);
}

// t1 = W^T u.  grid 8, block 256 (4 waves x 128 rows each).
__global__ void sigma1(const float* __restrict__ W, const float* __restrict__ u,
                       float* __restrict__ t1) {
  __shared__ float part[4][64];
  const int lane = threadIdx.x & 63, wv = threadIdx.x >> 6;
  const int col = blockIdx.x * 64 + lane;
  float s = 0.f;
  for (int r = wv * 128; r < wv * 128 + 128; ++r)
    s += W[(size_t)r * Z_ + col] * u[r];
  part[wv][lane] = s;
  __syncthreads();
  if (wv == 0)
    t1[col] = part[0][lane] + part[1][lane] + part[2][lane] + part[3][lane];
}

__global__ void sigma1b(const float* __restrict__ t1, float* __restrict__ invn) {
  __shared__ float red[256];
  int t = threadIdx.x;
  float v0 = t1[t], v1 = t1[t + 256];
  red[t] = v0 * v0 + v1 * v1;
  __syncthreads();
  for (int s = 128; s > 0; s >>= 1) {
    if (t < s) red[t] += red[t + s];
    __syncthreads();
  }
  if (t == 0) invn[0] = 1.0f / (sqrtf(red[0]) + 1e-12f);
}

// t2 = W @ (t1 * invn).  grid 128, block 256 (wave per row).
__global__ void sigma2(const float* __restrict__ W, const float* __restrict__ t1,
                       const float* __restrict__ invn, float* __restrict__ t2) {
  const int lane = threadIdx.x & 63, wv = threadIdx.x >> 6;
  const int row = blockIdx.x * 4 + wv;
  float s = 0.f;
  for (int c = lane; c < Z_; c += 64) s += W[(size_t)row * Z_ + c] * t1[c];
#pragma unroll
  for (int off = 32; off > 0; off >>= 1) s += __shfl_down(s, off);
  if (lane == 0) t2[row] = s * invn[0];
}

__global__ void sigma3(const float* __restrict__ t2, float* __restrict__ inv_sig) {
  __shared__ float red[256];
  int t = threadIdx.x;
  float v0 = t2[t], v1 = t2[t + 256];
  red[t] = v0 * v0 + v1 * v1;
  __syncthreads();
  for (int s = 128; s > 0; s >>= 1) {
    if (t < s) red[t] += red[t + s];
    __syncthreads();
  }
  if (t == 0) {
    float s2  = red[0];
    float sig = s2 / (sqrtf(s2) + 1e-12f);
    inv_sig[0] = 1.0f / sig;
  }
}

// dvec[row] = dot(w_ih[row], lin_b) for row in [0, 6144)
__global__ __launch_bounds__(256) void dots_k(const float* __restrict__ w,
                                              const float* __restrict__ lb,
                                              float* __restrict__ dvec) {
  const int wave = threadIdx.x >> 6, lane = threadIdx.x & 63;
#pragma unroll
  for (int i = 0; i < 4; ++i) {
    int row = blockIdx.x * 16 + wave * 4 + i;
    float s = 0.f;
    for (int c = lane; c < Z_; c += 64) s += w[(size_t)row * Z_ + c] * lb[c];
#pragma unroll
    for (int off = 32; off > 0; off >>= 1) s += __shfl_down(s, off);
    if (lane == 0) dvec[row] = s;
  }
}

__global__ void consts_k(const float* __restrict__ b_ih, const float* __restrict__ b_hh,
                         const float* __restrict__ dvec,
                         float* __restrict__ c0r, float* __restrict__ c0z,
                         float* __restrict__ c0n,
                         float* __restrict__ c1r, float* __restrict__ c1z,
                         float* __restrict__ c1n, float* __restrict__ chn) {
  int j = blockIdx.x * 256 + threadIdx.x;
  float br = b_ih[j], bz = b_ih[H_ + j], bn = b_ih[2 * H_ + j];
  float hr = b_hh[j], hz = b_hh[H_ + j], hn = b_hh[2 * H_ + j];
  c0r[j] = br + hr; c0z[j] = bz + hz; c0n[j] = bn; chn[j] = hn;
  c1r[j] = br + hr + dvec[j];
  c1z[j] = bz + hz + dvec[H_ + j];
  c1n[j] = bn + dvec[2 * H_ + j];
}

// BN over batch per (t,z) + transpose [T,B,Z] -> [B,T,Z]. Grid (16, 8).
__global__ __launch_bounds__(256) void bn_k(const float* __restrict__ outs,
                                            float* __restrict__ y) {
  __shared__ float s_sum[4][64], s_sq[4][64], s_mean[64], s_inv[64];
  const int t = blockIdx.x, zb = blockIdx.y;
  const int zl = threadIdx.x & 63, bp = threadIdx.x >> 6;
  const int z = zb * 64 + zl;
  float sum = 0.f, sq = 0.f;
  for (int b = bp * 64; b < bp * 64 + 64; ++b) {
    float v = outs[(size_t)(t * 256 + b) * Z_ + z];
    sum += v; sq += v * v;
  }
  s_sum[bp][zl] = sum; s_sq[bp][zl] = sq;
  __syncthreads();
  if (bp == 0) {
    float S = s_sum[0][zl] + s_sum[1][zl] + s_sum[2][zl] + s_sum[3][zl];
    float Q = s_sq[0][zl] + s_sq[1][zl] + s_sq[2][zl] + s_sq[3][zl];
    float mean = S * (1.0f / 256.0f);
    float var  = Q * (1.0f / 256.0f) - mean * mean;
    s_mean[zl] = mean;
    s_inv[zl]  = rsqrtf(var + 1e-5f);
  }
  __syncthreads();
  const float mean = s_mean[zl], inv = s_inv[zl];
  for (int b = bp * 64; b < bp * 64 + 64; ++b) {
    float v = outs[(size_t)(t * 256 + b) * Z_ + z];
    y[(size_t)(b * T_ + t) * Z_ + z] = (v - mean) * inv;
  }
}

// ---------------------------------------------------------------------------
extern "C" void kernel_launch(void* const* d_in, const int* in_sizes, int n_in,
                              void* d_out, int out_size, void* d_ws, size_t ws_size,
                              hipStream_t stream) {
  const float* z     = (const float*)d_in[0];
  const float* fc_w  = (const float*)d_in[1];
  const float* fc_b  = (const float*)d_in[2];
  const float* fc_u  = (const float*)d_in[3];
  const float* w_ih  = (const float*)d_in[4];
  const float* w_hh  = (const float*)d_in[5];
  const float* b_ih  = (const float*)d_in[6];
  const float* b_hh  = (const float*)d_in[7];
  const float* lin_w = (const float*)d_in[8];
  const float* lin_b = (const float*)d_in[9];
  float* out = (float*)d_out;

  char* ws = (char*)d_ws;
  size_t off = 0;
  auto alloc = [&](size_t bytes) -> void* {
    off = (off + 255) & ~(size_t)255;
    void* p = ws + off;
    off += bytes;
    return p;
  };
  unsigned short* w_ih_q   = (unsigned short*)alloc((size_t)H3_ * Z_ * 2);
  unsigned short* w_hhn_q  = (unsigned short*)alloc((size_t)H_ * H_ * 2);
  unsigned short* lin_w_q  = (unsigned short*)alloc((size_t)Z_ * H_ * 2);
  unsigned short* lin_wT_q = (unsigned short*)alloc((size_t)Z_ * H_ * 2);
  unsigned short* fc_w_q   = (unsigned short*)alloc((size_t)Z_ * Z_ * 2);
  unsigned short* z_q      = (unsigned short*)alloc((size_t)B_ * Z_ * 2);
  unsigned short* x0_q     = (unsigned short*)alloc((size_t)B_ * Z_ * 2);
  unsigned short* Wsum_r   = (unsigned short*)alloc((size_t)H_ * H_ * 2);
  unsigned short* Wsum_z   = (unsigned short*)alloc((size_t)H_ * H_ * 2);
  unsigned short* Wn_c     = (unsigned short*)alloc((size_t)H_ * H_ * 2);
  unsigned short* Hhist    = (unsigned short*)alloc((size_t)T_ * B_ * H_ * 2);
  float* h_f32 = (float*)alloc((size_t)2 * B_ * H_ * 4);
  float* outs  = (float*)alloc((size_t)T_ * B_ * Z_ * 4);
  float* c0r = (float*)alloc(H_ * 4);
  float* c0z = (float*)alloc(H_ * 4);
  float* c0n = (float*)alloc(H_ * 4);
  float* c1r = (float*)alloc(H_ * 4);
  float* c1z = (float*)alloc(H_ * 4);
  float* c1n = (float*)alloc(H_ * 4);
  float* chn = (float*)alloc(H_ * 4);
  float* dvec = (float*)alloc(H3_ * 4);
  float* t1v = (float*)alloc(Z_ * 4);
  float* t2v = (float*)alloc(Z_ * 4);
  float* invn = (float*)alloc(256);
  float* invsig = (float*)alloc(256);
  (void)in_sizes; (void)n_in; (void)out_size; (void)ws_size;

  auto q4 = [&](const float* s, unsigned short* dst, size_t n) {
    int n4 = (int)(n / 4);
    quantk<<<dim3((n4 + 255) / 256), dim3(256), 0, stream>>>(s, dst, n4);
  };
  q4(z, z_q, (size_t)B_ * Z_);
  q4(fc_w, fc_w_q, (size_t)Z_ * Z_);
  q4(w_ih, w_ih_q, (size_t)H3_ * Z_);
  q4(w_hh + (size_t)2 * H_ * H_, w_hhn_q, (size_t)H_ * H_);
  q4(lin_w, lin_w_q, (size_t)Z_ * H_);
  transq<<<dim3(64, 16), 256, 0, stream>>>(lin_w, lin_wT_q);
  sigma1<<<8, 256, 0, stream>>>(fc_w, fc_u, t1v);
  sigma1b<<<1, 256, 0, stream>>>(t1v, invn);
  sigma2<<<128, 256, 0, stream>>>(fc_w, t1v, invn, t2v);
  sigma3<<<1, 256, 0, stream>>>(t2v, invsig);
  dots_k<<<384, 256, 0, stream>>>(w_ih, lin_b, dvec);
  consts_k<<<8, 256, 0, stream>>>(b_ih, b_hh, dvec, c0r, c0z, c0n, c1r, c1z, c1n, chn);

  // x0 = (z @ fc_w^T) * inv_sigma + fc_b   -> bf16
  gemm_bt<<<dim3(B_ / 32, Z_ / 64), 256, 0, stream>>>(
      z_q, fc_w_q, Z_, nullptr, 0, fc_b, invsig, x0_q, nullptr, Z_);

  // W_comb_g = w_ih_g @ lin_w (+ w_hh_g for r,z) -> bf16 [2048][2048]
  for (int g = 0; g < 3; ++g) {
    const float* adds = (g < 2) ? (w_hh + (size_t)g * H_ * H_) : nullptr;
    unsigned short* outw = (g == 0) ? Wsum_r : (g == 1) ? Wsum_z : Wn_c;
    gemm_bt64<<<dim3(H_ / 64, H_ / 64), 256, 0, stream>>>(
        w_ih_q + (size_t)g * H_ * Z_, lin_wT_q, Z_, adds, H_, nullptr,
        outw, nullptr, H_);
  }

  for (int t = 0; t < T_; ++t) {
    if (t == 0) {
      gru_step2<<<256, 256, 0, stream>>>(
          x0_q, Z_,
          w_ih_q, w_ih_q + (size_t)H_ * Z_, w_ih_q + (size_t)2 * H_ * Z_,
          w_hhn_q /* dummy, scaled by 0 */,
          c0r, c0z, c0n, chn, 0.0f, nullptr, h_f32, Hhist);
    } else {
      gru_step2<<<256, 256, 0, stream>>>(
          Hhist + (size_t)(t - 1) * B_ * H_, H_,
          Wsum_r, Wsum_z, Wn_c, w_hhn_q,
          c1r, c1z, c1n, chn, 1.0f,
          h_f32 + (size_t)((t - 1) & 1) * B_ * H_,
          h_f32 + (size_t)(t & 1) * B_ * H_,
          Hhist + (size_t)t * B_ * H_);
    }
  }

  // outs[t*256+b][z] = Hhist[t][b] @ lin_w^T + lin_b   (f32)
  gemm_bt64<<<dim3(T_ * B_ / 64, Z_ / 64), 256, 0, stream>>>(
      Hhist, lin_w_q, H_, nullptr, 0, lin_b, nullptr, outs, Z_);

  bn_k<<<dim3(T_, Z_ / 64), 256, 0, stream>>>(outs, out);
}